// Round 1
// baseline (949.101 us; speedup 1.0000x reference)
//
#include <hip/hip_runtime.h>

#define M_ROWS 200000
#define DIM1   320
#define OUTD   416

static __device__ __forceinline__ float4 ld4(const float* p) {
    return *reinterpret_cast<const float4*>(p);
}

__global__ __launch_bounds__(256, 2)
void tp_rowlane_kernel(const float* __restrict__ x1,
                       const float* __restrict__ x2,
                       const float* __restrict__ w000,
                       const float* __restrict__ w011,
                       const float* __restrict__ w101,
                       const float* __restrict__ w110,
                       const float* __restrict__ w112,
                       float* __restrict__ out) {
    const int m = blockIdx.x * blockDim.x + threadIdx.x;
    if (m >= M_ROWS) return;

    constexpr float INV3 = 0.57735026918962576f;  // 1/sqrt(3)
    constexpr float INV6 = 0.40824829046386302f;  // 1/sqrt(6)

    const float* __restrict__ x1r = x1 + (size_t)m * DIM1;      // x1s: 128 floats
    const float* __restrict__ x1v = x1r + 128;                  // x1v: 64*3 floats
    float* __restrict__ outr = out + (size_t)m * OUTD;

    const float s2  = x2[(size_t)m * 4 + 0];
    const float v2x = x2[(size_t)m * 4 + 1];
    const float v2y = x2[(size_t)m * 4 + 2];
    const float v2z = x2[(size_t)m * 4 + 3];

    // ================= out0 : 128 cols, 2 chunks of 64 =================
    for (int wc = 0; wc < 2; ++wc) {
        float acc[64];
        #pragma unroll
        for (int i = 0; i < 64; ++i) acc[i] = 0.0f;

        // P1: a[w] = sum_u x1s[u] * W000[u][w]
        for (int u = 0; u < 128; ++u) {
            const float x = x1r[u];
            const float* wr = w000 + u * 128 + wc * 64;
            #pragma unroll
            for (int q = 0; q < 16; ++q) {
                float4 wv = ld4(wr + 4 * q);
                acc[4*q+0] += x * wv.x; acc[4*q+1] += x * wv.y;
                acc[4*q+2] += x * wv.z; acc[4*q+3] += x * wv.w;
            }
        }
        #pragma unroll
        for (int i = 0; i < 64; ++i) acc[i] *= s2;

        // P2: += (1/sqrt3) * sum_u (x1v[u].v2) * W110[u][w]
        for (int u = 0; u < 64; ++u) {
            const float ax = x1v[u*3+0], ay = x1v[u*3+1], az = x1v[u*3+2];
            const float d = (ax * v2x + ay * v2y + az * v2z) * INV3;
            const float* wr = w110 + u * 128 + wc * 64;
            #pragma unroll
            for (int q = 0; q < 16; ++q) {
                float4 wv = ld4(wr + 4 * q);
                acc[4*q+0] += d * wv.x; acc[4*q+1] += d * wv.y;
                acc[4*q+2] += d * wv.z; acc[4*q+3] += d * wv.w;
            }
        }

        float4* o = reinterpret_cast<float4*>(outr + wc * 64);
        #pragma unroll
        for (int q = 0; q < 16; ++q)
            o[q] = make_float4(acc[4*q+0], acc[4*q+1], acc[4*q+2], acc[4*q+3]);
    }

    // ================= out1 : 64 w-cols x 3 j, 2 chunks of 32 w =================
    for (int wc = 0; wc < 2; ++wc) {
        float b[32];
        float e[3][32];
        #pragma unroll
        for (int i = 0; i < 32; ++i) { b[i] = 0.0f; e[0][i] = 0.0f; e[1][i] = 0.0f; e[2][i] = 0.0f; }

        // b[w] = sum_u x1s[u] * W011[u][w]
        for (int u = 0; u < 128; ++u) {
            const float x = x1r[u];
            const float* wr = w011 + u * 64 + wc * 32;
            #pragma unroll
            for (int q = 0; q < 8; ++q) {
                float4 wv = ld4(wr + 4 * q);
                b[4*q+0] += x * wv.x; b[4*q+1] += x * wv.y;
                b[4*q+2] += x * wv.z; b[4*q+3] += x * wv.w;
            }
        }
        // e[j][w] = sum_u x1v[u][j] * W101[u][w]
        for (int u = 0; u < 64; ++u) {
            const float ax = x1v[u*3+0], ay = x1v[u*3+1], az = x1v[u*3+2];
            const float* wr = w101 + u * 64 + wc * 32;
            #pragma unroll
            for (int q = 0; q < 8; ++q) {
                float4 wv = ld4(wr + 4 * q);
                e[0][4*q+0] += ax * wv.x; e[0][4*q+1] += ax * wv.y;
                e[0][4*q+2] += ax * wv.z; e[0][4*q+3] += ax * wv.w;
                e[1][4*q+0] += ay * wv.x; e[1][4*q+1] += ay * wv.y;
                e[1][4*q+2] += ay * wv.z; e[1][4*q+3] += ay * wv.w;
                e[2][4*q+0] += az * wv.x; e[2][4*q+1] += az * wv.y;
                e[2][4*q+2] += az * wv.z; e[2][4*q+3] += az * wv.w;
            }
        }

        // out1[w][j] = INV3*(v2[j]*b[w] + s2*e[j][w]) at flat 128 + w*3 + j
        const float v2a[3] = {v2x, v2y, v2z};
        float4* o = reinterpret_cast<float4*>(outr + 128 + wc * 96);
        #pragma unroll
        for (int q = 0; q < 24; ++q) {
            float vals[4];
            #pragma unroll
            for (int l = 0; l < 4; ++l) {
                const int t = 4 * q + l;      // compile-time after unroll
                const int w = t / 3;
                const int j = t % 3;
                vals[l] = INV3 * (v2a[j] * b[w] + s2 * e[j][w]);
            }
            o[q] = make_float4(vals[0], vals[1], vals[2], vals[3]);
        }
    }

    // ================= out2 : 32 w-cols x 3 k, single chunk =================
    {
        float f[3][32];
        #pragma unroll
        for (int i = 0; i < 32; ++i) { f[0][i] = 0.0f; f[1][i] = 0.0f; f[2][i] = 0.0f; }

        for (int u = 0; u < 64; ++u) {
            const float ax = x1v[u*3+0], ay = x1v[u*3+1], az = x1v[u*3+2];
            const float cx = ay * v2z - az * v2y;
            const float cy = az * v2x - ax * v2z;
            const float cz = ax * v2y - ay * v2x;
            const float* wr = w112 + u * 32;
            #pragma unroll
            for (int q = 0; q < 8; ++q) {
                float4 wv = ld4(wr + 4 * q);
                f[0][4*q+0] += cx * wv.x; f[0][4*q+1] += cx * wv.y;
                f[0][4*q+2] += cx * wv.z; f[0][4*q+3] += cx * wv.w;
                f[1][4*q+0] += cy * wv.x; f[1][4*q+1] += cy * wv.y;
                f[1][4*q+2] += cy * wv.z; f[1][4*q+3] += cy * wv.w;
                f[2][4*q+0] += cz * wv.x; f[2][4*q+1] += cz * wv.y;
                f[2][4*q+2] += cz * wv.z; f[2][4*q+3] += cz * wv.w;
            }
        }

        // out2[w][k] = INV6 * f[k][w] at flat 320 + w*3 + k
        float4* o = reinterpret_cast<float4*>(outr + 320);
        #pragma unroll
        for (int q = 0; q < 24; ++q) {
            float vals[4];
            #pragma unroll
            for (int l = 0; l < 4; ++l) {
                const int t = 4 * q + l;
                const int w = t / 3;
                const int k = t % 3;
                vals[l] = INV6 * f[k][w];
            }
            o[q] = make_float4(vals[0], vals[1], vals[2], vals[3]);
        }
    }
}

extern "C" void kernel_launch(void* const* d_in, const int* in_sizes, int n_in,
                              void* d_out, int out_size, void* d_ws, size_t ws_size,
                              hipStream_t stream) {
    const float* x1   = (const float*)d_in[0];
    const float* x2   = (const float*)d_in[1];
    const float* w000 = (const float*)d_in[2];
    const float* w011 = (const float*)d_in[3];
    const float* w101 = (const float*)d_in[4];
    const float* w110 = (const float*)d_in[5];
    const float* w112 = (const float*)d_in[6];
    // d_in[7] = w3j111 (eps/sqrt6) — folded into the cross-product formula.
    float* out = (float*)d_out;

    dim3 block(256);
    dim3 grid((M_ROWS + 255) / 256);
    tp_rowlane_kernel<<<grid, block, 0, stream>>>(x1, x2, w000, w011, w101, w110, w112, out);
}

// Round 6
// 363.442 us; speedup vs baseline: 2.6114x; 2.6114x over previous
//
#include <hip/hip_runtime.h>

#define M_ROWS 200000
#define NROWS  64            // rows per block
#define NBLK   3125          // 200000 / 64, exact
#define DIM1   320
#define OUTD   416
#define FSTR   196           // feat row stride (floats): 16B-aligned, odd/49 dword rotation

#define SCAL_STR 9
#define SCAL_OFF (NROWS * FSTR)                  // floats
#define LDS_FLOATS (SCAL_OFF + NROWS * SCAL_STR) // 12544 + 576 = 13120 -> 52480 B

typedef __attribute__((ext_vector_type(4))) float f32x4;

static __device__ __forceinline__ float4 ld4(const float* p) {
    return *reinterpret_cast<const float4*>(p);
}

__global__ __launch_bounds__(256, 2)
void tp_valu_v6(const float* __restrict__ x1,
                const float* __restrict__ x2,
                const float* __restrict__ w000,
                const float* __restrict__ w011,
                const float* __restrict__ w101,
                const float* __restrict__ w110,
                const float* __restrict__ w112,
                float* __restrict__ out) {
    __shared__ float lds[LDS_FLOATS];
    float* feat = lds;
    float* scal = lds + SCAL_OFF;

    constexpr float INV3 = 0.57735026918962576f;   // 1/sqrt(3)
    constexpr float INV6 = 0.40824829046386302f;   // 1/sqrt(6)

    const int t   = threadIdx.x;
    const int row = t & 63;                        // staging row; also compute lane=row
    const int q   = t >> 6;                        // wave id = staging quarter
    const int wvu = __builtin_amdgcn_readfirstlane(q);  // wave-uniform (SGPR)
    const long rbase = (long)blockIdx.x * NROWS;

    const float* x1r = x1 + (rbase + row) * DIM1;
    float* frS = feat + row * FSTR;

    // x2 scalars for this row (kept in regs for staging; LDS copy for epilogues)
    const float4 xr2 = ld4(x2 + (rbase + row) * 4);
    const float s2 = xr2.x, vx = xr2.y, vy = xr2.z, vz = xr2.w;
    if (q == 0) {
        scal[row*SCAL_STR+0] = s2;
        scal[row*SCAL_STR+1] = s2 * INV3;
        scal[row*SCAL_STR+2] = vx * INV3;
        scal[row*SCAL_STR+3] = vy * INV3;
        scal[row*SCAL_STR+4] = vz * INV3;
    }

    // ---------------- stage S: featA = [x1s raw (0..127) | d*INV3 (128..191)] ----------------
    {
        #pragma unroll
        for (int i = 0; i < 8; ++i) {
            float4 v = ld4(x1r + q*32 + 4*i);
            *reinterpret_cast<float4*>(frS + q*32 + 4*i) = v;
        }
        float qf[48];
        #pragma unroll
        for (int c = 0; c < 12; ++c) {
            float4 v = ld4(x1r + 128 + 48*q + 4*c);
            qf[4*c+0]=v.x; qf[4*c+1]=v.y; qf[4*c+2]=v.z; qf[4*c+3]=v.w;
        }
        #pragma unroll
        for (int i = 0; i < 16; ++i) {
            const int u = 16*q + i;
            frS[128 + u] = (qf[3*i]*vx + qf[3*i+1]*vy + qf[3*i+2]*vz) * INV3;
        }
    }
    __syncthreads();

    const float* frC = feat + row * FSTR;          // lane = row for compute phases

    // ---------------- P1: out0, cols c0..c0+31 ----------------
    {
        const int c0 = wvu * 32;
        float accA[32], accD[32];
        #pragma unroll
        for (int i = 0; i < 32; ++i) { accA[i] = 0.f; accD[i] = 0.f; }

        #pragma unroll 2
        for (int kt = 0; kt < 32; ++kt) {
            f32x4 fq = *reinterpret_cast<const f32x4*>(frC + 4*kt);
            #pragma unroll
            for (int dk = 0; dk < 4; ++dk) {
                const float fv = fq[dk];
                const float* wp = w000 + (4*kt+dk)*128 + c0;
                #pragma unroll
                for (int j = 0; j < 8; ++j) {
                    float4 wq = ld4(wp + 4*j);
                    accA[4*j+0] += fv*wq.x; accA[4*j+1] += fv*wq.y;
                    accA[4*j+2] += fv*wq.z; accA[4*j+3] += fv*wq.w;
                }
            }
        }
        #pragma unroll 2
        for (int kt = 0; kt < 16; ++kt) {
            f32x4 fq = *reinterpret_cast<const f32x4*>(frC + 128 + 4*kt);
            #pragma unroll
            for (int dk = 0; dk < 4; ++dk) {
                const float fv = fq[dk];
                const float* wp = w110 + (4*kt+dk)*128 + c0;
                #pragma unroll
                for (int j = 0; j < 8; ++j) {
                    float4 wq = ld4(wp + 4*j);
                    accD[4*j+0] += fv*wq.x; accD[4*j+1] += fv*wq.y;
                    accD[4*j+2] += fv*wq.z; accD[4*j+3] += fv*wq.w;
                }
            }
        }
        const float s2r = scal[row*SCAL_STR+0];
        float* orow = out + (rbase + row)*OUTD + c0;
        #pragma unroll
        for (int j = 0; j < 8; ++j) {
            float4 o;
            o.x = s2r*accA[4*j+0] + accD[4*j+0];
            o.y = s2r*accA[4*j+1] + accD[4*j+1];
            o.z = s2r*accA[4*j+2] + accD[4*j+2];
            o.w = s2r*accA[4*j+3] + accD[4*j+3];
            *reinterpret_cast<float4*>(orow + 4*j) = o;
        }
    }

    // ---------------- P2: out1 b-part, cols c1..c1+15 (acc held across barriers) ----------------
    const int c1 = wvu * 16;
    float accB[16];
    #pragma unroll
    for (int i = 0; i < 16; ++i) accB[i] = 0.f;
    {
        #pragma unroll 2
        for (int kt = 0; kt < 32; ++kt) {
            f32x4 fq = *reinterpret_cast<const f32x4*>(frC + 4*kt);
            #pragma unroll
            for (int dk = 0; dk < 4; ++dk) {
                const float fv = fq[dk];
                const float* wp = w011 + (4*kt+dk)*64 + c1;
                #pragma unroll
                for (int j = 0; j < 4; ++j) {
                    float4 wq = ld4(wp + 4*j);
                    accB[4*j+0] += fv*wq.x; accB[4*j+1] += fv*wq.y;
                    accB[4*j+2] += fv*wq.z; accB[4*j+3] += fv*wq.w;
                }
            }
        }
    }
    __syncthreads();

    // ---------------- stage T: featT = [v0 (0..63) | v1 (64..127) | v2 (128..191)] ----------------
    {
        float qf[48];
        #pragma unroll
        for (int c = 0; c < 12; ++c) {
            float4 v = ld4(x1r + 128 + 48*q + 4*c);
            qf[4*c+0]=v.x; qf[4*c+1]=v.y; qf[4*c+2]=v.z; qf[4*c+3]=v.w;
        }
        #pragma unroll
        for (int i = 0; i < 16; ++i) {
            const int u = 16*q + i;
            frS[u]       = qf[3*i+0];
            frS[64 + u]  = qf[3*i+1];
            frS[128 + u] = qf[3*i+2];
        }
    }
    __syncthreads();

    // ---------------- P3: out1 e-part + epilogue ----------------
    {
        float accE0[16], accE1[16], accE2[16];
        #pragma unroll
        for (int i = 0; i < 16; ++i) { accE0[i]=0.f; accE1[i]=0.f; accE2[i]=0.f; }

        #pragma unroll 2
        for (int ut = 0; ut < 16; ++ut) {
            f32x4 f0 = *reinterpret_cast<const f32x4*>(frC + 4*ut);
            f32x4 f1 = *reinterpret_cast<const f32x4*>(frC + 64 + 4*ut);
            f32x4 f2 = *reinterpret_cast<const f32x4*>(frC + 128 + 4*ut);
            #pragma unroll
            for (int du = 0; du < 4; ++du) {
                const float a0 = f0[du], a1 = f1[du], a2 = f2[du];
                const float* wp = w101 + (4*ut+du)*64 + c1;
                #pragma unroll
                for (int j = 0; j < 4; ++j) {
                    float4 wq = ld4(wp + 4*j);
                    accE0[4*j+0] += a0*wq.x; accE0[4*j+1] += a0*wq.y;
                    accE0[4*j+2] += a0*wq.z; accE0[4*j+3] += a0*wq.w;
                    accE1[4*j+0] += a1*wq.x; accE1[4*j+1] += a1*wq.y;
                    accE1[4*j+2] += a1*wq.z; accE1[4*j+3] += a1*wq.w;
                    accE2[4*j+0] += a2*wq.x; accE2[4*j+1] += a2*wq.y;
                    accE2[4*j+2] += a2*wq.z; accE2[4*j+3] += a2*wq.w;
                }
            }
        }
        const float s2I = scal[row*SCAL_STR+1];
        const float vxI = scal[row*SCAL_STR+2];
        const float vyI = scal[row*SCAL_STR+3];
        const float vzI = scal[row*SCAL_STR+4];
        float vals[48];
        #pragma unroll
        for (int jj = 0; jj < 16; ++jj) {
            vals[3*jj+0] = vxI*accB[jj] + s2I*accE0[jj];
            vals[3*jj+1] = vyI*accB[jj] + s2I*accE1[jj];
            vals[3*jj+2] = vzI*accB[jj] + s2I*accE2[jj];
        }
        float* orow = out + (rbase + row)*OUTD + 128 + 3*c1;
        #pragma unroll
        for (int qq = 0; qq < 12; ++qq)
            *reinterpret_cast<float4*>(orow + 4*qq) =
                make_float4(vals[4*qq], vals[4*qq+1], vals[4*qq+2], vals[4*qq+3]);
    }
    __syncthreads();

    // ---------------- stage U: featC = [c0I | c1I | c2I] (cross(x1v, v2) * INV6) ----------------
    {
        float qf[48];
        #pragma unroll
        for (int c = 0; c < 12; ++c) {
            float4 v = ld4(x1r + 128 + 48*q + 4*c);
            qf[4*c+0]=v.x; qf[4*c+1]=v.y; qf[4*c+2]=v.z; qf[4*c+3]=v.w;
        }
        #pragma unroll
        for (int i = 0; i < 16; ++i) {
            const int u = 16*q + i;
            const float a0 = qf[3*i+0], a1 = qf[3*i+1], a2 = qf[3*i+2];
            frS[u]       = (a1*vz - a2*vy) * INV6;
            frS[64 + u]  = (a2*vx - a0*vz) * INV6;
            frS[128 + u] = (a0*vy - a1*vx) * INV6;
        }
    }
    __syncthreads();

    // ---------------- P4: out2, 24 cols per wave (w2 = 8*wvu + wl, kc = 0..2) ----------------
    {
        float accC[24];
        #pragma unroll
        for (int i = 0; i < 24; ++i) accC[i] = 0.f;
        const int wb = wvu * 8;

        #pragma unroll 2
        for (int ut = 0; ut < 16; ++ut) {
            f32x4 f0 = *reinterpret_cast<const f32x4*>(frC + 4*ut);
            f32x4 f1 = *reinterpret_cast<const f32x4*>(frC + 64 + 4*ut);
            f32x4 f2 = *reinterpret_cast<const f32x4*>(frC + 128 + 4*ut);
            #pragma unroll
            for (int du = 0; du < 4; ++du) {
                const float b0 = f0[du], b1 = f1[du], b2 = f2[du];
                const float* wp = w112 + (4*ut+du)*32 + wb;
                float4 wa = ld4(wp);
                float4 wbq = ld4(wp + 4);
                const float wvals[8] = {wa.x, wa.y, wa.z, wa.w, wbq.x, wbq.y, wbq.z, wbq.w};
                #pragma unroll
                for (int wl = 0; wl < 8; ++wl) {
                    accC[3*wl+0] += b0 * wvals[wl];
                    accC[3*wl+1] += b1 * wvals[wl];
                    accC[3*wl+2] += b2 * wvals[wl];
                }
            }
        }
        float* orow = out + (rbase + row)*OUTD + 320 + 24*wvu;
        #pragma unroll
        for (int qq = 0; qq < 6; ++qq)
            *reinterpret_cast<float4*>(orow + 4*qq) =
                make_float4(accC[4*qq], accC[4*qq+1], accC[4*qq+2], accC[4*qq+3]);
    }
}

extern "C" void kernel_launch(void* const* d_in, const int* in_sizes, int n_in,
                              void* d_out, int out_size, void* d_ws, size_t ws_size,
                              hipStream_t stream) {
    const float* x1   = (const float*)d_in[0];
    const float* x2   = (const float*)d_in[1];
    const float* w000 = (const float*)d_in[2];
    const float* w011 = (const float*)d_in[3];
    const float* w101 = (const float*)d_in[4];
    const float* w110 = (const float*)d_in[5];
    const float* w112 = (const float*)d_in[6];
    // d_in[7] = w3j111 — folded analytically (cross product / sqrt6).
    float* out = (float*)d_out;

    tp_valu_v6<<<dim3(NBLK), dim3(256), 0, stream>>>(
        x1, x2, w000, w011, w101, w110, w112, out);
}